// Round 1
// baseline (207.949 us; speedup 1.0000x reference)
//
#include <hip/hip_runtime.h>
#include <math.h>

// Problem constants (fixed by the reference):
// B=2, N=131072 (=2^17), K=9, P=4, D=4, S=1, CI=8, CO=8
#define N_PTS 131072
#define KNB   9
#define PD    16          // P*D*S = 16 (p,d) cells per point
#define CIN   8
#define COUT  8
#define PTS_PER_BLK 16    // points per block (256 threads / 16 pd-threads)
#define THREADS 256
#define AMP_STRIDE 68     // 64 + 4 pad -> pd lanes land 4 banks apart (2-way, free)

__global__ __launch_bounds__(THREADS) void polnormal_kernel(
    const float* __restrict__ x,      // (B, N, CI)
    const float* __restrict__ dx,     // (B, N, K)
    const float* __restrict__ dy,     // (B, N, K)
    const int*   __restrict__ adj,    // (N, K)
    const float* __restrict__ phis,   // (P,)
    const float* __restrict__ dists,  // (D,)
    const float* __restrict__ sigma,  // (S,) = (1,)
    const float* __restrict__ amp,    // (P, D, S, CI, CO) = (pd, c, o)
    float*       __restrict__ out)    // (B, N, P, D, S, CO)
{
    __shared__ float s_dx[PTS_PER_BLK * KNB];
    __shared__ float s_dy[PTS_PER_BLK * KNB];
    __shared__ int   s_adj[PTS_PER_BLK * KNB];
    __shared__ float s_x[PTS_PER_BLK * KNB * CIN];   // [i][k][c]
    __shared__ float s_amp[PD * AMP_STRIDE];

    const int  tid    = threadIdx.x;
    const long base_g = (long)blockIdx.x * PTS_PER_BLK;   // flattened (b,n); 16 | N so no b-straddle
    const int  b      = (int)(base_g >> 17);              // N = 2^17
    const int  base_n = (int)(base_g & (N_PTS - 1));

    // Stage dx/dy/adj: 144 contiguous elements each.
    if (tid < PTS_PER_BLK * KNB) {
        s_dx[tid]  = dx[base_g * KNB + tid];
        s_dy[tid]  = dy[base_g * KNB + tid];
        s_adj[tid] = adj[(long)base_n * KNB + tid];
    }
    // Stage amplitudes with bank-conflict padding: flat = pd*64 + c*8 + o.
    for (int t = tid; t < PD * CIN * COUT; t += THREADS) {
        int pd = t >> 6;
        int co = t & 63;
        s_amp[pd * AMP_STRIDE + co] = amp[t];
    }
    __syncthreads();   // s_adj ready

    // Gather neighbor features: 144 rows x 32 B, as 288 float4 loads.
    for (int t = tid; t < PTS_PER_BLK * KNB * 2; t += THREADS) {
        int pair = t >> 1;            // i*K + k
        int half = t & 1;
        long row = (long)s_adj[pair];
        const float4* src = (const float4*)(x + ((long)b * N_PTS + row) * CIN);
        ((float4*)s_x)[pair * 2 + half] = src[half];
    }
    __syncthreads();

    // One thread per (point i, pd cell).
    const int i  = tid >> 4;
    const int pd = tid & 15;
    const int p  = pd >> 2;
    const int d  = pd & 3;

    const float phi  = phis[p];
    const float dist = dists[d];
    float sn, cs;
    __sincosf(phi, &sn, &cs);
    const float mux = cs * dist;
    const float muy = sn * dist;

    float sig = fmaxf(sigma[0], 1e-10f);
    const float s2         = sig * sig;
    const float neg_inv2s2 = -0.5f / s2;
    const float norm       = rsqrtf(6.283185307179586f * s2);

    float wx[CIN];
#pragma unroll
    for (int c = 0; c < CIN; ++c) wx[c] = 0.0f;

#pragma unroll
    for (int k = 0; k < KNB; ++k) {
        float ddx = s_dx[i * KNB + k] - mux;
        float ddy = s_dy[i * KNB + k] - muy;
        float r2  = ddx * ddx + ddy * ddy;
        float w   = __expf(neg_inv2s2 * r2) * norm;
        const float* xr = &s_x[(i * KNB + k) * CIN];
#pragma unroll
        for (int c = 0; c < CIN; ++c) wx[c] += w * xr[c];
    }

    float acc[COUT];
#pragma unroll
    for (int o = 0; o < COUT; ++o) acc[o] = 0.0f;
#pragma unroll
    for (int c = 0; c < CIN; ++c) {
        const float wc = wx[c];
        const float* ar = &s_amp[pd * AMP_STRIDE + c * COUT];
#pragma unroll
        for (int o = 0; o < COUT; ++o) acc[o] += wc * ar[o];
    }

    // out[((g*16)+pd)*8 + o] : 32 B/thread, contiguous across pd-threads.
    float4* op = (float4*)(out + ((base_g + i) * PD + pd) * COUT);
    op[0] = make_float4(acc[0], acc[1], acc[2], acc[3]);
    op[1] = make_float4(acc[4], acc[5], acc[6], acc[7]);
}

extern "C" void kernel_launch(void* const* d_in, const int* in_sizes, int n_in,
                              void* d_out, int out_size, void* d_ws, size_t ws_size,
                              hipStream_t stream) {
    const float* x     = (const float*)d_in[0];
    const float* dx    = (const float*)d_in[1];
    const float* dy    = (const float*)d_in[2];
    const int*   adj   = (const int*)  d_in[3];
    const float* phis  = (const float*)d_in[4];
    const float* dists = (const float*)d_in[5];
    const float* sigma = (const float*)d_in[6];
    const float* amp   = (const float*)d_in[7];
    float* out = (float*)d_out;

    const int total_pts = 2 * N_PTS;                 // B*N = 262144
    const int grid = total_pts / PTS_PER_BLK;        // 16384 blocks
    polnormal_kernel<<<grid, THREADS, 0, stream>>>(x, dx, dy, adj, phis, dists,
                                                   sigma, amp, out);
}